// Round 1
// 1362.972 us; speedup vs baseline: 1.0122x; 1.0122x over previous
//
#include <hip/hip_runtime.h>
#include <cstddef>

#define NNODES 25000
#define NEDGES 400000

__device__ __forceinline__ float clip100(float x) {
    return fminf(fmaxf(x, -100.0f), 100.0f);
}
__device__ __forceinline__ float silu_f(float x) {
    return x / (1.0f + __expf(-x));
}

// ---------------------------------------------------------------------------
// CSR build: histogram -> scan -> scatter.
// Round 3 change: k_scatter materializes {edge, receiver} pairs (int2) and a
// per-slot float4 dir record in sender-sorted order.  This removes the
// two-level dependent gather chain (eids[j] -> receivers[e] -> data) that was
// serializing the edge kernel at ~1500+ cycles/edge.
// ---------------------------------------------------------------------------
__global__ void k_hist(const int* __restrict__ senders, int* __restrict__ counts)
{
    int e = blockIdx.x * 256 + threadIdx.x;
    if (e < NEDGES) atomicAdd(&counts[senders[e]], 1);
}

// One block, 1024 threads.  Each thread serially prefixes 25 contiguous
// counts in registers, then one 1024-wide Hillis-Steele scan of the
// per-thread totals (~22 barriers vs ~500 in the chunked version).
__global__ void k_scan(const int* __restrict__ counts,
                       int* __restrict__ rowstart, int* __restrict__ cursor)
{
    __shared__ int buf[1024];
    const int tid = threadIdx.x;
    const int ITEMS = 25;                 // 1024*25 = 25600 >= NNODES
    const int base = tid * ITEMS;
    int local[ITEMS];
    int sum = 0;
    #pragma unroll
    for (int i = 0; i < ITEMS; ++i) {
        int idx = base + i;
        int c = (idx < NNODES) ? counts[idx] : 0;
        local[i] = sum;                   // exclusive prefix within thread
        sum += c;
    }
    buf[tid] = sum;
    __syncthreads();
    #pragma unroll
    for (int off = 1; off < 1024; off <<= 1) {
        int t = (tid >= off) ? buf[tid - off] : 0;
        __syncthreads();
        buf[tid] += t;
        __syncthreads();
    }
    const int excl = buf[tid] - sum;      // exclusive prefix across threads
    #pragma unroll
    for (int i = 0; i < ITEMS; ++i) {
        int idx = base + i;
        if (idx < NNODES) {
            int v = excl + local[i];
            rowstart[idx] = v;
            cursor[idx] = v;
        }
    }
    if (tid == 1023) rowstart[NNODES] = buf[1023];
}

__global__ void k_scatter(const int* __restrict__ senders,
                          const int* __restrict__ receivers,
                          const float* __restrict__ dir_ij,
                          int* __restrict__ cursor,
                          int2* __restrict__ epair,
                          float4* __restrict__ edir)
{
    int e = blockIdx.x * 256 + threadIdx.x;
    if (e < NEDGES) {
        int pos = atomicAdd(&cursor[senders[e]], 1);
        epair[pos] = make_int2(e, receivers[e]);
        edir[pos] = make_float4(dir_ij[e * 3 + 0], dir_ij[e * 3 + 1],
                                dir_ij[e * 3 + 2], 0.0f);
        // epair/edir have NEDGES+1 slots; the pad slot is only ever
        // prefetched (never dereferenced), so no init needed.
    }
}

// ---------------------------------------------------------------------------
// Kernel 1: x = silu(s @ Wi1 + bi1) @ Wi2 + bi2        (per node, 128->128->384)
// ---------------------------------------------------------------------------
__global__ __launch_bounds__(256, 4) void k_node_mlp(
    const float* __restrict__ s,
    const float* __restrict__ Wi1, const float* __restrict__ bi1,
    const float* __restrict__ Wi2, const float* __restrict__ bi2,
    float* __restrict__ x)
{
    __shared__ __align__(16) float s_lds[8][128];
    __shared__ __align__(16) float h_lds[8][128];
    const int tid = threadIdx.x;
    const int g = tid >> 6;
    const int l = tid & 63;
    const int n0 = 2 * g, n1 = n0 + 1;
    const long gn0 = (long)blockIdx.x * 8 + n0;
    const long gn1 = gn0 + 1;

    #pragma unroll
    for (int i = 0; i < 2; ++i) {
        int h = l + 64 * i;
        s_lds[n0][h] = s[gn0 * 128 + h];
        s_lds[n1][h] = s[gn1 * 128 + h];
    }

    float accA[2][2];
    accA[0][0] = accA[1][0] = bi1[l];
    accA[0][1] = accA[1][1] = bi1[l + 64];
    #pragma unroll 4
    for (int k = 0; k < 128; ++k) {
        float w0 = Wi1[k * 128 + l];
        float w1 = Wi1[k * 128 + l + 64];
        float i0 = s_lds[n0][k];
        float i1 = s_lds[n1][k];
        accA[0][0] = fmaf(i0, w0, accA[0][0]);
        accA[0][1] = fmaf(i0, w1, accA[0][1]);
        accA[1][0] = fmaf(i1, w0, accA[1][0]);
        accA[1][1] = fmaf(i1, w1, accA[1][1]);
    }
    h_lds[n0][l]      = silu_f(accA[0][0]);
    h_lds[n0][l + 64] = silu_f(accA[0][1]);
    h_lds[n1][l]      = silu_f(accA[1][0]);
    h_lds[n1][l + 64] = silu_f(accA[1][1]);

    float accB[2][6];
    #pragma unroll
    for (int i = 0; i < 6; ++i) {
        float b = bi2[l + 64 * i];
        accB[0][i] = b; accB[1][i] = b;
    }
    #pragma unroll 4
    for (int k = 0; k < 128; ++k) {
        float i0 = h_lds[n0][k];
        float i1 = h_lds[n1][k];
        #pragma unroll
        for (int i = 0; i < 6; ++i) {
            float w = Wi2[k * 384 + l + 64 * i];
            accB[0][i] = fmaf(i0, w, accB[0][i]);
            accB[1][i] = fmaf(i1, w, accB[1][i]);
        }
    }
    #pragma unroll
    for (int i = 0; i < 6; ++i) {
        x[gn0 * 384 + l + 64 * i] = accB[0][i];
        x[gn1 * 384 + l + 64 * i] = accB[1][i];
    }
}

// ---------------------------------------------------------------------------
// Kernel 2: sorted edge aggregation.  One wave per sender node; lane l owns
// channels {2l, 2l+1} (float2).  Per edge: 1 int2 + 1 float4 prefetch + 9
// float2 loads (vs 21 scalar loads + 2-level dependent chain in round 2).
// All accumulation in registers, coalesced float2 stores, no atomics.
// acc layout per node: [ds(128) | dv0(128) | dv1(128) | dv2(128)]
// ---------------------------------------------------------------------------
__global__ __launch_bounds__(256, 8) void k_edge_sorted(
    const float* __restrict__ x, const float* __restrict__ v,
    const float* __restrict__ Wij,
    const int* __restrict__ rowstart,
    const int2* __restrict__ epair,
    const float4* __restrict__ edir,
    float* __restrict__ acc)
{
    const int wave = threadIdx.x >> 6;
    const int l = threadIdx.x & 63;
    const int n = blockIdx.x * 4 + wave;
    if (n >= NNODES) return;

    float2 ds  = make_float2(0.0f, 0.0f);
    float2 dv0 = make_float2(0.0f, 0.0f);
    float2 dv1 = make_float2(0.0f, 0.0f);
    float2 dv2 = make_float2(0.0f, 0.0f);

    const int jb = rowstart[n];
    const int je = rowstart[n + 1];
    if (jb < je) {
        int2   pr = epair[jb];   // {edge id, receiver}
        float4 dr = edir[jb];
        for (int j = jb; j < je; ++j) {
            const int2   cur = pr;
            const float4 d   = dr;
            pr = epair[j + 1];   // j+1 <= NEDGES: pad slot, never dereferenced
            dr = edir[j + 1];

            const float2* __restrict__ wr =
                (const float2*)(Wij + (size_t)cur.x * 384);
            const float2* __restrict__ xr =
                (const float2*)(x + (size_t)cur.y * 384);
            const float2* __restrict__ vr =
                (const float2*)(v + (size_t)cur.y * 384);

            float2 w0 = wr[l], w1 = wr[64 + l], w2 = wr[128 + l];
            float2 x0 = xr[l], x1 = xr[64 + l], x2 = xr[128 + l];
            float2 v0 = vr[l], v1 = vr[64 + l], v2 = vr[128 + l];

            ds.x = fmaf(w0.x, x0.x, ds.x);
            ds.y = fmaf(w0.y, x0.y, ds.y);
            float ax = w1.x * x1.x, ay = w1.y * x1.y;
            float bx = w2.x * x2.x, by = w2.y * x2.y;
            dv0.x = fmaf(ax, d.x, fmaf(bx, v0.x, dv0.x));
            dv0.y = fmaf(ay, d.x, fmaf(by, v0.y, dv0.y));
            dv1.x = fmaf(ax, d.y, fmaf(bx, v1.x, dv1.x));
            dv1.y = fmaf(ay, d.y, fmaf(by, v1.y, dv1.y));
            dv2.x = fmaf(ax, d.z, fmaf(bx, v2.x, dv2.x));
            dv2.y = fmaf(ay, d.z, fmaf(by, v2.y, dv2.y));
        }
    }

    float2* __restrict__ arow = (float2*)(acc + (size_t)n * 512);
    arow[l]        = ds;
    arow[64 + l]   = dv0;
    arow[128 + l]  = dv1;
    arow[192 + l]  = dv2;
}

// ---------------------------------------------------------------------------
// Kernel 3: node update (unchanged).
// ---------------------------------------------------------------------------
__global__ __launch_bounds__(256, 4) void k_update(
    const float* __restrict__ s_in, const float* __restrict__ v_in,
    const float* __restrict__ acc,
    const float* __restrict__ Wm1, const float* __restrict__ bm1,
    const float* __restrict__ Wm2, const float* __restrict__ bm2,
    const float* __restrict__ Wv,
    float* __restrict__ s_out, float* __restrict__ v_out)
{
    __shared__ __align__(16) float ts[8][256];     // [s+ds | vnorm]
    __shared__ __align__(16) float v_cur[8][384];  // v + clip(dv)
    __shared__ __align__(16) float hid[8][128];
    const int tid = threadIdx.x;
    const int g = tid >> 6;
    const int l = tid & 63;
    const int n0 = 2 * g, n1 = n0 + 1;
    const long gn0 = (long)blockIdx.x * 8 + n0;
    const long gn1 = gn0 + 1;

    #pragma unroll
    for (int i = 0; i < 2; ++i) {
        int h = l + 64 * i;
        ts[n0][h] = s_in[gn0 * 128 + h] + clip100(acc[gn0 * 512 + h]);
        ts[n1][h] = s_in[gn1 * 128 + h] + clip100(acc[gn1 * 512 + h]);
    }
    float vreg[2][6];
    #pragma unroll
    for (int i = 0; i < 6; ++i) {
        int r = l + 64 * i;
        vreg[0][i] = v_in[gn0 * 384 + r] + clip100(acc[gn0 * 512 + 128 + r]);
        vreg[1][i] = v_in[gn1 * 384 + r] + clip100(acc[gn1 * 512 + 128 + r]);
        v_cur[n0][r] = vreg[0][i];
        v_cur[n1][r] = vreg[1][i];
    }

    float aV[2][3][4];
    #pragma unroll
    for (int j = 0; j < 2; ++j)
        #pragma unroll
        for (int d = 0; d < 3; ++d)
            #pragma unroll
            for (int i = 0; i < 4; ++i) aV[j][d][i] = 0.0f;
    #pragma unroll 4
    for (int k = 0; k < 128; ++k) {
        float w[4];
        #pragma unroll
        for (int i = 0; i < 4; ++i) w[i] = Wv[k * 256 + l + 64 * i];
        #pragma unroll
        for (int d = 0; d < 3; ++d) {
            float i0 = v_cur[n0][d * 128 + k];
            float i1 = v_cur[n1][d * 128 + k];
            #pragma unroll
            for (int i = 0; i < 4; ++i) {
                aV[0][d][i] = fmaf(i0, w[i], aV[0][d][i]);
                aV[1][d][i] = fmaf(i1, w[i], aV[1][d][i]);
            }
        }
    }

    float vv[2][2];
    #pragma unroll
    for (int j = 0; j < 2; ++j) {
        int nn = (j == 0) ? n0 : n1;
        #pragma unroll
        for (int i = 0; i < 2; ++i) {
            int h = l + 64 * i;
            float l0 = aV[j][0][i],     l1 = aV[j][1][i],     l2 = aV[j][2][i];
            float r0 = aV[j][0][i + 2], r1 = aV[j][1][i + 2], r2 = aV[j][2][i + 2];
            ts[nn][128 + h] = sqrtf(fmaf(r0, r0, fmaf(r1, r1, r2 * r2)) + 1e-8f);
            vv[j][i] = fmaf(r0, l0, fmaf(r1, l1, r2 * l2));
        }
    }

    float aM[2][2];
    aM[0][0] = aM[1][0] = bm1[l];
    aM[0][1] = aM[1][1] = bm1[l + 64];
    #pragma unroll 4
    for (int k = 0; k < 256; ++k) {
        float w0 = Wm1[k * 128 + l];
        float w1 = Wm1[k * 128 + l + 64];
        float i0 = ts[n0][k];
        float i1 = ts[n1][k];
        aM[0][0] = fmaf(i0, w0, aM[0][0]);
        aM[0][1] = fmaf(i0, w1, aM[0][1]);
        aM[1][0] = fmaf(i1, w0, aM[1][0]);
        aM[1][1] = fmaf(i1, w1, aM[1][1]);
    }
    hid[n0][l]      = silu_f(aM[0][0]);
    hid[n0][l + 64] = silu_f(aM[0][1]);
    hid[n1][l]      = silu_f(aM[1][0]);
    hid[n1][l + 64] = silu_f(aM[1][1]);

    float aB[2][6];
    #pragma unroll
    for (int i = 0; i < 6; ++i) {
        float b = bm2[l + 64 * i];
        aB[0][i] = b; aB[1][i] = b;
    }
    #pragma unroll 4
    for (int k = 0; k < 128; ++k) {
        float i0 = hid[n0][k];
        float i1 = hid[n1][k];
        #pragma unroll
        for (int i = 0; i < 6; ++i) {
            float w = Wm2[k * 384 + l + 64 * i];
            aB[0][i] = fmaf(i0, w, aB[0][i]);
            aB[1][i] = fmaf(i1, w, aB[1][i]);
        }
    }

    #pragma unroll
    for (int j = 0; j < 2; ++j) {
        int nn = (j == 0) ? n0 : n1;
        long gn = (j == 0) ? gn0 : gn1;
        #pragma unroll
        for (int i = 0; i < 2; ++i) {
            int h = l + 64 * i;
            s_out[gn * 128 + h] = ts[nn][h] + clip100(aB[j][i] + aB[j][4 + i] * vv[j][i]);
        }
        #pragma unroll
        for (int i = 0; i < 6; ++i) {
            int r = l + 64 * i;
            int d = i >> 1;
            int b = i & 1;
            float vl = aV[j][d][b];
            float dvu = aB[j][2 + b];
            v_out[gn * 384 + r] = vreg[j][i] + clip100(vl * dvu);
        }
    }
}

extern "C" void kernel_launch(void* const* d_in, const int* in_sizes, int n_in,
                              void* d_out, int out_size, void* d_ws, size_t ws_size,
                              hipStream_t stream) {
    const float* s   = (const float*)d_in[0];
    const float* v   = (const float*)d_in[1];
    const float* dir = (const float*)d_in[2];
    const float* Wij = (const float*)d_in[3];
    const float* Wi1 = (const float*)d_in[4];
    const float* bi1 = (const float*)d_in[5];
    const float* Wi2 = (const float*)d_in[6];
    const float* bi2 = (const float*)d_in[7];
    const float* Wm1 = (const float*)d_in[8];
    const float* bm1 = (const float*)d_in[9];
    const float* Wm2 = (const float*)d_in[10];
    const float* bm2 = (const float*)d_in[11];
    const float* Wv  = (const float*)d_in[12];
    const int* senders   = (const int*)d_in[13];
    const int* receivers = (const int*)d_in[14];

    // workspace layout (floats unless noted); all bases 16B-aligned
    float* xbuf = (float*)d_ws;                            // NNODES*384
    float* accb = xbuf + (size_t)NNODES * 384;             // NNODES*512
    float4* edir = (float4*)(accb + (size_t)NNODES * 512); // NEDGES+1 float4
    int2* epair = (int2*)(edir + (size_t)NEDGES + 1);      // NEDGES+1 int2
    int* counts   = (int*)(epair + (size_t)NEDGES + 1);    // NNODES
    int* rowstart = counts + NNODES;                       // NNODES+1 (+pad)
    int* cursor   = rowstart + NNODES + 8;                 // NNODES
    float* s_out = (float*)d_out;
    float* v_out = s_out + (size_t)NNODES * 128;

    hipMemsetAsync(counts, 0, (size_t)NNODES * sizeof(int), stream);
    k_hist<<<(NEDGES + 255) / 256, 256, 0, stream>>>(senders, counts);
    k_scan<<<1, 1024, 0, stream>>>(counts, rowstart, cursor);
    k_scatter<<<(NEDGES + 255) / 256, 256, 0, stream>>>(
        senders, receivers, dir, cursor, epair, edir);
    k_node_mlp<<<NNODES / 8, 256, 0, stream>>>(s, Wi1, bi1, Wi2, bi2, xbuf);
    k_edge_sorted<<<(NNODES + 3) / 4, 256, 0, stream>>>(
        xbuf, v, Wij, rowstart, epair, edir, accb);
    k_update<<<NNODES / 8, 256, 0, stream>>>(s, v, accb, Wm1, bm1, Wm2, bm2, Wv,
                                             s_out, v_out);
}